// Round 7
// baseline (287.110 us; speedup 1.0000x reference)
//
#include <hip/hip_runtime.h>
#include <math.h>

#define H 1024
#define S 32768
#define NBLK 256
#define SENT 0x5EA50001u

__device__ __forceinline__ float agent_load(float* p) {
    return __hip_atomic_load(p, __ATOMIC_RELAXED, __HIP_MEMORY_SCOPE_AGENT);
}
__device__ __forceinline__ void agent_store(float* p, float v) {
    __hip_atomic_store(p, v, __ATOMIC_RELAXED, __HIP_MEMORY_SCOPE_AGENT);
}

// 256 blocks, 1 per CU (co-resident). __syncthreads() drains vmcnt(0) so the
// block's agent stores are at the coherence point before the flag is set.
__device__ __forceinline__ void grid_barrier(unsigned int* flags, int bid, int tid) {
    __syncthreads();
    if (tid == 0)
        __hip_atomic_store(&flags[bid], SENT, __ATOMIC_RELEASE, __HIP_MEMORY_SCOPE_AGENT);
    while (__hip_atomic_load(&flags[tid], __ATOMIC_ACQUIRE, __HIP_MEMORY_SCOPE_AGENT) != SENT)
        __builtin_amdgcn_s_sleep(4);
    __syncthreads();
}

__global__ __launch_bounds__(256) void fused_attn_kernel(
    const float* __restrict__ hidden, const float* __restrict__ enc,
    const float* __restrict__ W_lin,  const float* __restrict__ b_lin,
    const float* __restrict__ W_attn, const float* __restrict__ b_attn,
    float* h, float* energy, float* blockmax, float* blocksum,
    unsigned int* bar0, unsigned int* bar1, unsigned int* bar2,
    float* __restrict__ out)
{
    __shared__ float xs[H];
    __shared__ float red[4];
    const int tid = threadIdx.x, wave = tid >> 6, lane = tid & 63, bid = blockIdx.x;
    const float4* xs4 = reinterpret_cast<const float4*>(xs);

    // ---------- Phase A: h[4b..4b+3] = W_lin rows . hidden + b_lin ----------
    {
        const int row = bid * 4 + wave;
        const float4* x4 = reinterpret_cast<const float4*>(hidden);
        const float4* Wr = reinterpret_cast<const float4*>(W_lin + (size_t)row * H);
        float4 wv[4], ev[4];
        #pragma unroll
        for (int k = 0; k < 4; ++k) { wv[k] = Wr[k * 64 + lane]; ev[k] = x4[k * 64 + lane]; }
        float acc = 0.f;
        #pragma unroll
        for (int k = 0; k < 4; ++k)
            acc += wv[k].x * ev[k].x + wv[k].y * ev[k].y + wv[k].z * ev[k].z + wv[k].w * ev[k].w;
        #pragma unroll
        for (int off = 32; off > 0; off >>= 1) acc += __shfl_xor(acc, off, 64);
        if (lane == 0) agent_store(&h[row], acc + b_lin[row]);
    }
    grid_barrier(bar0, bid, tid);

    // ---------- Phase B: energy[4b..4b+3] = W_attn rows . h + b_attn --------
    {
        #pragma unroll
        for (int j = 0; j < 4; ++j) xs[tid + 256 * j] = agent_load(&h[tid + 256 * j]);
        __syncthreads();
        const int row = bid * 4 + wave;
        const float4* Wr = reinterpret_cast<const float4*>(W_attn + (size_t)row * H);
        float4 wv[4], ev[4];
        #pragma unroll
        for (int k = 0; k < 4; ++k) { wv[k] = Wr[k * 64 + lane]; ev[k] = xs4[k * 64 + lane]; }
        float acc = 0.f;
        #pragma unroll
        for (int k = 0; k < 4; ++k)
            acc += wv[k].x * ev[k].x + wv[k].y * ev[k].y + wv[k].z * ev[k].z + wv[k].w * ev[k].w;
        #pragma unroll
        for (int off = 32; off > 0; off >>= 1) acc += __shfl_xor(acc, off, 64);
        if (lane == 0) agent_store(&energy[row], acc + b_attn[row]);
        __syncthreads();   // xs reuse safety before barrier's own syncs
    }
    grid_barrier(bar1, bid, tid);

    // ---------- Phase C: 32 scores per wave (kept in registers) -------------
    float sc[32];
    float bm;
    const int wr0 = bid * 128 + wave * 32;      // this wave's 32 contiguous rows
    {
        #pragma unroll
        for (int j = 0; j < 4; ++j) xs[tid + 256 * j] = agent_load(&energy[tid + 256 * j]);
        __syncthreads();
        float4 ev[4];
        #pragma unroll
        for (int k = 0; k < 4; ++k) ev[k] = xs4[k * 64 + lane];  // energy in regs, reused 8x

        float wmax = -INFINITY;
        #pragma unroll
        for (int it = 0; it < 8; ++it) {
            const float4* Er = reinterpret_cast<const float4*>(enc + (size_t)(wr0 + it * 4) * H);
            float4 wv[4][4];
            #pragma unroll
            for (int p = 0; p < 4; ++p)
                #pragma unroll
                for (int k = 0; k < 4; ++k)
                    wv[p][k] = Er[p * 256 + k * 64 + lane];
            float a[4];
            #pragma unroll
            for (int p = 0; p < 4; ++p) {
                float s = 0.f;
                #pragma unroll
                for (int k = 0; k < 4; ++k)
                    s += wv[p][k].x * ev[k].x + wv[p][k].y * ev[k].y +
                         wv[p][k].z * ev[k].z + wv[p][k].w * ev[k].w;
                a[p] = s;
            }
            #pragma unroll
            for (int off = 32; off > 0; off >>= 1) {
                #pragma unroll
                for (int p = 0; p < 4; ++p) a[p] += __shfl_xor(a[p], off, 64);
            }
            #pragma unroll
            for (int p = 0; p < 4; ++p) {
                sc[it * 4 + p] = a[p];
                wmax = fmaxf(wmax, a[p]);
            }
        }
        if (lane == 0) red[wave] = wmax;
        __syncthreads();
        bm = fmaxf(fmaxf(red[0], red[1]), fmaxf(red[2], red[3]));
        float wsum = 0.f;                        // wave-uniform
        #pragma unroll
        for (int j = 0; j < 32; ++j) wsum += expf(sc[j] - bm);
        __syncthreads();
        if (lane == 0) red[wave] = wsum;
        __syncthreads();
        if (tid == 0) {
            agent_store(&blockmax[bid], bm);
            agent_store(&blocksum[bid], red[0] + red[1] + red[2] + red[3]);
        }
    }
    grid_barrier(bar2, bid, tid);

    // ---------- Phase D: global max/total (redundant per block), write out --
    {
        float m_t = agent_load(&blockmax[tid]);
        float s_t = agent_load(&blocksum[tid]);
        float m = m_t;
        #pragma unroll
        for (int off = 32; off > 0; off >>= 1) m = fmaxf(m, __shfl_xor(m, off, 64));
        if (lane == 0) red[wave] = m;
        __syncthreads();
        const float M = fmaxf(fmaxf(red[0], red[1]), fmaxf(red[2], red[3]));

        float t = s_t * expf(m_t - M);
        #pragma unroll
        for (int off = 32; off > 0; off >>= 1) t += __shfl_xor(t, off, 64);
        __syncthreads();
        if (lane == 0) red[wave] = t;
        __syncthreads();
        const float inv = 1.0f / (red[0] + red[1] + red[2] + red[3]);

        if (lane == 0) {
            float4* o4 = reinterpret_cast<float4*>(out);
            #pragma unroll
            for (int j = 0; j < 8; ++j) {
                o4[(wr0 >> 2) + j] = make_float4(
                    expf(sc[4 * j + 0] - M) * inv, expf(sc[4 * j + 1] - M) * inv,
                    expf(sc[4 * j + 2] - M) * inv, expf(sc[4 * j + 3] - M) * inv);
            }
        }
    }
}

extern "C" void kernel_launch(void* const* d_in, const int* in_sizes, int n_in,
                              void* d_out, int out_size, void* d_ws, size_t ws_size,
                              hipStream_t stream) {
    const float* hidden = (const float*)d_in[0];
    const float* enc    = (const float*)d_in[1];
    const float* W_lin  = (const float*)d_in[2];
    const float* b_lin  = (const float*)d_in[3];
    const float* W_attn = (const float*)d_in[4];
    const float* b_attn = (const float*)d_in[5];
    float* out = (float*)d_out;
    float* ws  = (float*)d_ws;

    float* h        = ws;                 // 1024
    float* energy   = ws + H;             // 1024
    float* blockmax = ws + 2 * H;         // 256
    float* blocksum = ws + 2 * H + 256;   // 256
    unsigned int* bar0 = (unsigned int*)(ws + 2 * H + 512);        // 256
    unsigned int* bar1 = bar0 + 256;
    unsigned int* bar2 = bar1 + 256;

    fused_attn_kernel<<<NBLK, 256, 0, stream>>>(hidden, enc, W_lin, b_lin,
                                                W_attn, b_attn, h, energy,
                                                blockmax, blocksum,
                                                bar0, bar1, bar2, out);
}

// Round 8
// 228.666 us; speedup vs baseline: 1.2556x; 1.2556x over previous
//
#include <hip/hip_runtime.h>
#include <math.h>

#define H 1024
#define S 32768
#define NB3 1024                    // scores blocks: 4 waves x 8 rows = 32 rows/block
#define NFB 32                      // finalize blocks: 32*256*float4 = 32768 elems

__device__ __forceinline__ float wave_reduce_sum(float v) {
    #pragma unroll
    for (int off = 32; off > 0; off >>= 1) v += __shfl_xor(v, off, 64);
    return v;
}

// y[row] = dot(W[row,:], x) + b[row].  One wave per row, 4 rows per block.
__global__ __launch_bounds__(256) void gemv_kernel(const float* __restrict__ W,
                                                   const float* __restrict__ x,
                                                   const float* __restrict__ b,
                                                   float* __restrict__ y) {
    const int tid = threadIdx.x;
    const int wave = tid >> 6, lane = tid & 63;
    const int row = blockIdx.x * 4 + wave;
    const float4* Wr = reinterpret_cast<const float4*>(W + (size_t)row * H);
    const float4* x4 = reinterpret_cast<const float4*>(x);

    float4 w[4], e[4];
    #pragma unroll
    for (int k = 0; k < 4; ++k) w[k] = Wr[k * 64 + lane];
    #pragma unroll
    for (int k = 0; k < 4; ++k) e[k] = x4[k * 64 + lane];

    float acc = 0.f;
    #pragma unroll
    for (int k = 0; k < 4; ++k)
        acc += w[k].x * e[k].x + w[k].y * e[k].y + w[k].z * e[k].z + w[k].w * e[k].w;
    acc = wave_reduce_sum(acc);
    if (lane == 0) y[row] = acc + b[row];
}

// MEASUREMENT VARIANT: every score computed twice and averaged ((a+a)/2 is
// bit-exact in fp32). Doubles this kernel's duration so it cracks the
// rocprof top-5 (threshold ~77us) and we finally get dur/FETCH/VALUBusy on it.
// The asm jitter inside the unroll-1 pass loop defeats load CSE/LICM.
__global__ __launch_bounds__(256) void scores_kernel(
    const float* __restrict__ enc,
    const float* __restrict__ energy,
    float* __restrict__ scores,      // [S]   ws
    float* __restrict__ blockmax,    // [NB3] ws
    float* __restrict__ blocksum)    // [NB3] ws
{
    __shared__ float redm[4], reds[4];
    const int tid = threadIdx.x;
    const int wave = tid >> 6, lane = tid & 63;
    const int bid  = blockIdx.x;

    const float4* e4 = reinterpret_cast<const float4*>(energy);
    float4 e[4];
    #pragma unroll
    for (int k = 0; k < 4; ++k) e[k] = e4[k * 64 + lane];

    const int wr0 = (bid * 4 + wave) * 8;          // this wave's 8 contiguous rows
    float accs[8];
    #pragma unroll
    for (int j = 0; j < 8; ++j) accs[j] = 0.f;

    #pragma unroll 1
    for (int pass = 0; pass < 2; ++pass) {
        int jit;                                   // always 0, opaque to compiler
        asm volatile("v_mov_b32 %0, 0" : "=v"(jit));
        const float4* Eb = reinterpret_cast<const float4*>(enc) + jit;

        #pragma unroll
        for (int batch = 0; batch < 2; ++batch) {
            const float4* Er = Eb + (size_t)(wr0 + batch * 4) * 256;
            float4 w[4][4];
            #pragma unroll
            for (int p = 0; p < 4; ++p)
                #pragma unroll
                for (int k = 0; k < 4; ++k)
                    w[p][k] = Er[p * 256 + k * 64 + lane];
            float a[4];
            #pragma unroll
            for (int p = 0; p < 4; ++p) {
                float s = 0.f;
                #pragma unroll
                for (int k = 0; k < 4; ++k)
                    s += w[p][k].x * e[k].x + w[p][k].y * e[k].y +
                         w[p][k].z * e[k].z + w[p][k].w * e[k].w;
                a[p] = s;
            }
            #pragma unroll
            for (int off = 32; off > 0; off >>= 1) {
                #pragma unroll
                for (int p = 0; p < 4; ++p) a[p] += __shfl_xor(a[p], off, 64);
            }
            #pragma unroll
            for (int p = 0; p < 4; ++p) accs[batch * 4 + p] += a[p];
        }
    }
    #pragma unroll
    for (int j = 0; j < 8; ++j) accs[j] *= 0.5f;   // (a+a)/2 == a exactly

    float wmax = -INFINITY;
    #pragma unroll
    for (int j = 0; j < 8; ++j) wmax = fmaxf(wmax, accs[j]);

    if (lane == 0) {
        float4* s4 = reinterpret_cast<float4*>(scores);
        s4[(wr0 >> 2) + 0] = make_float4(accs[0], accs[1], accs[2], accs[3]);
        s4[(wr0 >> 2) + 1] = make_float4(accs[4], accs[5], accs[6], accs[7]);
        redm[wave] = wmax;
    }
    __syncthreads();
    const float bm = fmaxf(fmaxf(redm[0], redm[1]), fmaxf(redm[2], redm[3]));

    float wsum = 0.f;                              // wave-uniform
    #pragma unroll
    for (int j = 0; j < 8; ++j) wsum += expf(accs[j] - bm);
    if (lane == 0) reds[wave] = wsum;
    __syncthreads();
    if (tid == 0) {
        blockmax[bid] = bm;
        blocksum[bid] = reds[0] + reds[1] + reds[2] + reds[3];
    }
}

// NFB blocks: every block redundantly reduces the 1024 {max,sum} pairs
// (8 KB, L2-resident), then normalizes its slice: one float4 per thread.
__global__ __launch_bounds__(256) void finalize_kernel(
    const float* __restrict__ scores,
    const float* __restrict__ blockmax,
    const float* __restrict__ blocksum,
    float* __restrict__ out)
{
    __shared__ float redm[4], reds[4];
    const int tid = threadIdx.x;
    const int wave = tid >> 6, lane = tid & 63;

    float m = -INFINITY;
    #pragma unroll
    for (int i = 0; i < NB3 / 256; ++i) m = fmaxf(m, blockmax[tid + i * 256]);
    #pragma unroll
    for (int off = 32; off > 0; off >>= 1) m = fmaxf(m, __shfl_xor(m, off, 64));
    if (lane == 0) redm[wave] = m;
    __syncthreads();
    const float M = fmaxf(fmaxf(redm[0], redm[1]), fmaxf(redm[2], redm[3]));

    float t = 0.f;
    #pragma unroll
    for (int i = 0; i < NB3 / 256; ++i) {
        const int b = tid + i * 256;
        t += blocksum[b] * expf(blockmax[b] - M);
    }
    t = wave_reduce_sum(t);
    if (lane == 0) reds[wave] = t;
    __syncthreads();
    const float inv = 1.0f / (reds[0] + reds[1] + reds[2] + reds[3]);

    const int idx = blockIdx.x * 256 + tid;
    const float4 v = reinterpret_cast<const float4*>(scores)[idx];
    reinterpret_cast<float4*>(out)[idx] =
        make_float4(expf(v.x - M) * inv, expf(v.y - M) * inv,
                    expf(v.z - M) * inv, expf(v.w - M) * inv);
}

extern "C" void kernel_launch(void* const* d_in, const int* in_sizes, int n_in,
                              void* d_out, int out_size, void* d_ws, size_t ws_size,
                              hipStream_t stream) {
    const float* hidden = (const float*)d_in[0];
    const float* enc    = (const float*)d_in[1];
    const float* W_lin  = (const float*)d_in[2];
    const float* b_lin  = (const float*)d_in[3];
    const float* W_attn = (const float*)d_in[4];
    const float* b_attn = (const float*)d_in[5];
    float* out = (float*)d_out;
    float* ws  = (float*)d_ws;

    float* scores   = ws;                        // 32768
    float* blockmax = ws + S;                    // 1024
    float* blocksum = ws + S + NB3;              // 1024
    float* h        = ws + S + 2 * NB3;          // 1024
    float* energy   = ws + S + 2 * NB3 + H;      // 1024

    gemv_kernel<<<H / 4, 256, 0, stream>>>(W_lin, hidden, b_lin, h);
    gemv_kernel<<<H / 4, 256, 0, stream>>>(W_attn, h, b_attn, energy);
    scores_kernel<<<NB3, 256, 0, stream>>>(enc, energy, scores, blockmax, blocksum);
    finalize_kernel<<<NFB, 256, 0, stream>>>(scores, blockmax, blocksum, out);
}